// Round 1
// baseline (29108.545 us; speedup 1.0000x reference)
//
#include <hip/hip_runtime.h>
#include <math.h>

#define BB 16
#define TT 96
#define VV 32000
#define DW 512
#define DF 512
#define HH 1024
#define LLn 100
#define FF 64
#define EPSF 1e-8f
#define KX 2148   // a_prev(512)+wv(512)+wo(100)+h(1024)

__device__ __forceinline__ float wsum(float v){
  #pragma unroll
  for (int m=32;m>0;m>>=1) v += __shfl_xor(v,m);
  return v;
}
__device__ __forceinline__ float sigm(float x){ return 1.0f/(1.0f+expf(-x)); }
__device__ __forceinline__ float softplus(float x){ return x>20.0f ? x : log1pf(expf(x)); }

// gates[b][r] = W_ih[r].x_part + W_hh[r].h_part + b_ih[r]+b_hh[r]
__global__ __launch_bounds__(256) void k_gates(
    const float* __restrict__ Wih, const float* __restrict__ Whh,
    const float* __restrict__ bih, const float* __restrict__ bhh,
    const float* __restrict__ xf, float* __restrict__ gates)
{
  int wave = threadIdx.x >> 6, lane = threadIdx.x & 63;
  int r = blockIdx.x*4 + wave;
  const float4* W1 = (const float4*)(Wih + (size_t)r*1124);
  const float4* W2 = (const float4*)(Whh + (size_t)r*1024);
  const float4* X  = (const float4*)xf;   // stride 537 f4 per batch
  float acc[BB];
  #pragma unroll
  for (int b=0;b<BB;b++) acc[b]=0.f;
  for (int it=0; it<5; it++){
    int i = it*64 + lane;
    if (i < 281){
      float4 w = W1[i];
      #pragma unroll
      for (int b=0;b<BB;b++){
        float4 x = X[b*537 + i];
        acc[b] += w.x*x.x + w.y*x.y + w.z*x.z + w.w*x.w;
      }
    }
  }
  for (int it=0; it<4; it++){
    int i = it*64 + lane;
    float4 w = W2[i];
    #pragma unroll
    for (int b=0;b<BB;b++){
      float4 x = X[b*537 + 281 + i];
      acc[b] += w.x*x.x + w.y*x.y + w.z*x.z + w.w*x.w;
    }
  }
  #pragma unroll
  for (int b=0;b<BB;b++) acc[b] = wsum(acc[b]);
  if (lane==0){
    float bias = bih[r] + bhh[r];
    #pragma unroll
    for (int b=0;b<BB;b++) gates[b*4096 + r] = acc[b] + bias;
  }
}

// LSTM pointwise update + write h to xf/oe/oa; p==4 builds wv/wo for next step
__global__ void k_lstm(const float* __restrict__ gates, float* __restrict__ c,
                       float* __restrict__ xf, float* __restrict__ oe, float* __restrict__ oa,
                       const float* __restrict__ emb, const int* __restrict__ tw,
                       const int* __restrict__ tz, int t)
{
  int b = blockIdx.x, p = blockIdx.y, tid = threadIdx.x;
  if (p < 4){
    int j = p*256 + tid;
    const float* g = gates + b*4096;
    float ig = g[j], fg = g[1024+j], gg = g[2048+j], og = g[3072+j];
    float co = c[b*1024+j];
    float cn = sigm(fg)*co + sigm(ig)*tanhf(gg);
    float hn = sigm(og)*tanhf(cn);
    c[b*1024+j] = cn;
    xf[b*KX + 1124 + j] = hn;
    oe[b*1536 + j] = hn;
    oa[b*1536 + j] = hn;
  } else {
    int z = tz[b*TT + t], w = tw[b*TT + t];
    for (int d=tid; d<512; d+=256)
      xf[b*KX + 512 + d] = (z==0) ? emb[(size_t)w*512 + d] : 0.f;
    for (int l=tid; l<100; l+=256)
      xf[b*KX + 1024 + l] = (z==0) ? 0.f : (l==w ? 1.f : 0.f);
  }
}

// first-layer MLP, K=1536, up to 3 row-segments of 1024 (Wc1/Wv1/Wp1), relu
__global__ __launch_bounds__(256) void k_mlp1536(
    const float* __restrict__ Wa, const float* __restrict__ Wb, const float* __restrict__ Wc,
    const float* __restrict__ ba, const float* __restrict__ bb, const float* __restrict__ bc,
    const float* __restrict__ X, float* __restrict__ out, int ostride)
{
  int wave = threadIdx.x >> 6, lane = threadIdx.x & 63;
  int r = blockIdx.x*4 + wave;
  int seg = r >> 10, rl = r & 1023;
  const float* W  = (seg==0) ? Wa : (seg==1) ? Wb : Wc;
  const float* bi = (seg==0) ? ba : (seg==1) ? bb : bc;
  const float4* Wr = (const float4*)(W + (size_t)rl*1536);
  const float4* X4 = (const float4*)X;   // stride 384 f4
  float acc[BB];
  #pragma unroll
  for (int b=0;b<BB;b++) acc[b]=0.f;
  for (int it=0; it<6; it++){
    int i = it*64 + lane;
    float4 w = Wr[i];
    #pragma unroll
    for (int b=0;b<BB;b++){
      float4 x = X4[b*384 + i];
      acc[b] += w.x*x.x + w.y*x.y + w.z*x.z + w.w*x.w;
    }
  }
  #pragma unroll
  for (int b=0;b<BB;b++) acc[b] = wsum(acc[b]);
  if (lane==0){
    float bv = bi[rl];
    #pragma unroll
    for (int b=0;b<BB;b++){
      float v = acc[b] + bv;
      out[b*ostride + r] = fmaxf(v, 0.f);
    }
  }
}

// second-layer heads, K=1024, two row-segments with independent W/X/out, no relu
__global__ __launch_bounds__(256) void k_mlp1024(
    const float* __restrict__ Wa, const float* __restrict__ ba,
    const float* __restrict__ Xa, int xsa, float* __restrict__ Oa, int osa, int Ma,
    const float* __restrict__ Wb, const float* __restrict__ bb,
    const float* __restrict__ Xb, int xsb, float* __restrict__ Ob, int osb)
{
  int wave = threadIdx.x >> 6, lane = threadIdx.x & 63;
  int r = blockIdx.x*4 + wave;
  const float* W; const float* bi; const float4* X4; float* O; int os, rl, xs4;
  if (r < Ma){ W=Wa; bi=ba; X4=(const float4*)Xa; os=osa; rl=r;    xs4=xsa>>2; O=Oa; }
  else       { W=Wb; bi=bb; X4=(const float4*)Xb; os=osb; rl=r-Ma; xs4=xsb>>2; O=Ob; }
  const float4* Wr = (const float4*)(W + (size_t)rl*1024);
  float acc[BB];
  #pragma unroll
  for (int b=0;b<BB;b++) acc[b]=0.f;
  for (int it=0; it<4; it++){
    int i = it*64 + lane;
    float4 w = Wr[i];
    #pragma unroll
    for (int b=0;b<BB;b++){
      float4 x = X4[b*xs4 + i];
      acc[b] += w.x*x.x + w.y*x.y + w.z*x.z + w.w*x.w;
    }
  }
  #pragma unroll
  for (int b=0;b<BB;b++) acc[b] = wsum(acc[b]);
  if (lane==0){
    float bv = bi[rl];
    #pragma unroll
    for (int b=0;b<BB;b++) O[b*os + rl] = acc[b] + bv;
  }
}

// attention: scores, masked softmax-with-eps, loss_m, argmax -> a_vec into xf/oa
__global__ __launch_bounds__(256) void k_attn(
    const float* __restrict__ fe, const float* __restrict__ kfact,
    const int* __restrict__ ta, const int* __restrict__ nfp,
    float* __restrict__ xf, float* __restrict__ oa, float* __restrict__ loss, int t)
{
  __shared__ float sS[64];
  __shared__ int sIdx;
  int b = blockIdx.x, tid = threadIdx.x;
  int f = tid >> 2, q = tid & 3;
  const float4* fe4 = (const float4*)(fe + ((size_t)b*64 + f)*512);
  const float4* kf4 = (const float4*)(kfact + b*512);
  float acc = 0.f;
  for (int j=0;j<32;j++){
    int i = q*32 + j;
    float4 a = fe4[i], k = kf4[i];
    acc += a.x*k.x + a.y*k.y + a.z*k.z + a.w*k.w;
  }
  acc += __shfl_xor(acc,1);
  acc += __shfl_xor(acc,2);
  if (q==0) sS[f] = acc;
  __syncthreads();
  if (tid < 64){
    int nf = nfp[b];
    float s = sS[tid];
    float mx = s;
    #pragma unroll
    for (int m=32;m>0;m>>=1) mx = fmaxf(mx, __shfl_xor(mx,m));
    float p = expf(s - mx);
    float ps = wsum(p);
    p /= ps;
    bool mask = (tid < nf) || (tid == 63);
    float mval = mask ? (p + EPSF) : EPSF;
    float msum = wsum(mval);
    float bv = mval; int bi2 = tid;
    #pragma unroll
    for (int m=32;m>0;m>>=1){
      float ov = __shfl_xor(bv,m); int oi = __shfl_xor(bi2,m);
      if (ov > bv || (ov == bv && oi < bi2)){ bv = ov; bi2 = oi; }
    }
    int at = ta[b*TT + t];
    float mat = __shfl(mval, at);
    if (tid == 0){
      atomicAdd(loss, -(logf(mat) - logf(msum)));
      sIdx = bi2;
    }
  }
  __syncthreads();
  int ai = sIdx;
  const float* av = fe + ((size_t)b*64 + ai)*512;
  for (int d=tid; d<512; d+=256){
    float v = av[d];
    oa[b*1536 + 1024 + d] = v;
    xf[b*KX + d] = v;
  }
}

// z head + position head + their loss terms
__global__ __launch_bounds__(256) void k_posz(
    const float* __restrict__ tcvp, const float* __restrict__ Wc2, const float* __restrict__ bc2,
    const float* __restrict__ WP, const float* __restrict__ bP, const float* __restrict__ kpos,
    const float* __restrict__ pmask, const int* __restrict__ tw, const int* __restrict__ ta,
    const int* __restrict__ tz, float* __restrict__ loss, int t)
{
  __shared__ float kp[100], pp[100], red[4];
  int b = blockIdx.x, tid = threadIdx.x;
  if (tid < 100) kp[tid] = kpos[b*128 + tid];
  const float* tc = tcvp + (size_t)b*3072;
  float a = 0.f;
  for (int j=tid; j<1024; j+=256) a += Wc2[j]*tc[j];
  a = wsum(a);
  if ((tid&63)==0) red[tid>>6] = a;
  __syncthreads();
  if (tid < 100){
    float s = bP[tid];
    const float* wr = WP + tid*100;
    for (int j=0;j<100;j++) s += wr[j]*kp[j];
    pp[tid] = s;
  }
  __syncthreads();
  if (tid == 0){
    float u = red[0]+red[1]+red[2]+red[3] + bc2[0];
    int z = tz[b*TT+t], w = tw[b*TT+t], at = ta[b*TT+t];
    float tot = z ? softplus(-u) : softplus(u);
    if (z){
      float mx = -1e30f;
      for (int l=0;l<100;l++) mx = fmaxf(mx, pp[l]);
      float se = 0.f;
      for (int l=0;l<100;l++) se += expf(pp[l]-mx);
      const float* pm = pmask + ((size_t)b*64 + at)*100;
      float msum = 0.f, mw = 0.f;
      for (int l=0;l<100;l++){
        float m = pm[l]*(expf(pp[l]-mx)/se) + EPSF;
        msum += m;
        if (l==w) mw = m;
      }
      tot += -(logf(mw) - logf(msum));
    }
    atomicAdd(loss, tot);
  }
}

// vocab logits: lg[v][b] = emb[v] . k_voca[b]
__global__ __launch_bounds__(256) void k_vocab(
    const float* __restrict__ emb, const float* __restrict__ kv, float* __restrict__ lg)
{
  int wave = threadIdx.x >> 6, lane = threadIdx.x & 63;
  int r = blockIdx.x*4 + wave;
  int b = lane & 15, sl = lane >> 4;
  const float4* e4 = (const float4*)(emb + (size_t)r*512);
  const float4* k4 = (const float4*)(kv + b*512);
  float acc = 0.f;
  #pragma unroll 8
  for (int it=0; it<32; it++){
    int i = sl*32 + it;
    float4 w = e4[i], x = k4[i];
    acc += w.x*x.x + w.y*x.y + w.z*x.z + w.w*x.w;
  }
  acc += __shfl_xor(acc, 16);
  acc += __shfl_xor(acc, 32);
  if (sl == 0) lg[(size_t)r*16 + b] = acc;
}

// per-batch logsumexp over V + vocab loss term
__global__ __launch_bounds__(256) void k_vred(
    const float* __restrict__ lg, const int* __restrict__ tw, const int* __restrict__ tz,
    float* __restrict__ loss, int t)
{
  __shared__ float red[4];
  int b = blockIdx.x, tid = threadIdx.x;
  float mx = -1e30f;
  for (int v=tid; v<VV; v+=256) mx = fmaxf(mx, lg[(size_t)v*16+b]);
  #pragma unroll
  for (int m=32;m>0;m>>=1) mx = fmaxf(mx, __shfl_xor(mx,m));
  if ((tid&63)==0) red[tid>>6] = mx;
  __syncthreads();
  mx = fmaxf(fmaxf(red[0],red[1]), fmaxf(red[2],red[3]));
  __syncthreads();
  float s = 0.f;
  for (int v=tid; v<VV; v+=256) s += expf(lg[(size_t)v*16+b] - mx);
  s = wsum(s);
  if ((tid&63)==0) red[tid>>6] = s;
  __syncthreads();
  if (tid==0){
    s = red[0]+red[1]+red[2]+red[3];
    if (tz[b*TT+t]==0){
      int w = tw[b*TT+t];
      float lw = lg[(size_t)w*16+b] - (mx + logf(s));
      atomicAdd(loss, -lw);
    }
  }
}

// setup: e_k into oe[.,1024:1536], wv=emb[SOS] into xf
__global__ void k_setup(const float* __restrict__ fe, const int* __restrict__ nfp,
                        const float* __restrict__ emb, float* __restrict__ oe,
                        float* __restrict__ xf)
{
  int b = blockIdx.x, tid = threadIdx.x;
  int nf = nfp[b];
  for (int d=tid; d<512; d+=256){
    float s = 0.f;
    for (int f=0; f<nf; f++) s += fe[((size_t)b*64+f)*512 + d];
    oe[b*1536 + 1024 + d] = s / (float)nf;
    xf[b*KX + 512 + d] = emb[d];
  }
}

__global__ void k_out(const float* __restrict__ loss, float* __restrict__ out){
  out[0] = loss[0];
}

extern "C" void kernel_launch(void* const* d_in, const int* in_sizes, int n_in,
                              void* d_out, int out_size, void* d_ws, size_t ws_size,
                              hipStream_t stream)
{
  const float* fe   = (const float*)d_in[0];
  const float* pmask= (const float*)d_in[1];
  const float* emb  = (const float*)d_in[2];
  const float* Wih  = (const float*)d_in[3];
  const float* Whh  = (const float*)d_in[4];
  const float* bih  = (const float*)d_in[5];
  const float* bhh  = (const float*)d_in[6];
  const float* Wf1  = (const float*)d_in[7];
  const float* bf1  = (const float*)d_in[8];
  const float* Wf2  = (const float*)d_in[9];
  const float* bf2  = (const float*)d_in[10];
  const float* Wc1  = (const float*)d_in[11];
  const float* bc1  = (const float*)d_in[12];
  const float* Wc2  = (const float*)d_in[13];
  const float* bc2  = (const float*)d_in[14];
  const float* Wv1  = (const float*)d_in[15];
  const float* bv1  = (const float*)d_in[16];
  const float* Wv2  = (const float*)d_in[17];
  const float* bv2  = (const float*)d_in[18];
  const float* Wp1  = (const float*)d_in[19];
  const float* bp1  = (const float*)d_in[20];
  const float* Wp2  = (const float*)d_in[21];
  const float* bp2  = (const float*)d_in[22];
  const float* WP   = (const float*)d_in[23];
  const float* bP   = (const float*)d_in[24];
  const int* tw  = (const int*)d_in[25];
  const int* ta  = (const int*)d_in[26];
  const int* tz  = (const int*)d_in[27];
  const int* nfp = (const int*)d_in[28];

  float* w     = (float*)d_ws;
  float* loss  = w;                 // 16 (zeroed)
  float* xf    = w + 16;            // 16*2148 (zeroed)
  float* c     = w + 34384;         // 16*1024 (zeroed)
  float* gates = w + 50768;         // 16*4096
  float* oe    = w + 116304;        // 16*1536
  float* oa    = w + 140880;        // 16*1536
  float* tf    = w + 165456;        // 16*1024
  float* kfact = w + 181840;        // 16*512
  float* tcvp  = w + 190032;        // 16*3072
  float* kvoca = w + 239184;        // 16*512
  float* kpos  = w + 247376;        // 16*128
  float* lg    = w + 249424;        // 32000*16

  hipMemsetAsync(d_ws, 0, 50768*sizeof(float), stream);
  k_setup<<<16,256,0,stream>>>(fe, nfp, emb, oe, xf);

  for (int t=0; t<TT; t++){
    k_gates<<<1024,256,0,stream>>>(Wih,Whh,bih,bhh,xf,gates);
    k_lstm<<<dim3(16,5),256,0,stream>>>(gates,c,xf,oe,oa,emb,tw,tz,t);
    k_mlp1536<<<256,256,0,stream>>>(Wf1,Wf1,Wf1,bf1,bf1,bf1,oe,tf,1024);
    k_mlp1024<<<128,256,0,stream>>>(Wf2,bf2,tf,1024,kfact,512,512,
                                    Wf2,bf2,tf,1024,kfact,512);
    k_attn<<<16,256,0,stream>>>(fe,kfact,ta,nfp,xf,oa,loss,t);
    k_mlp1536<<<768,256,0,stream>>>(Wc1,Wv1,Wp1,bc1,bv1,bp1,oa,tcvp,3072);
    k_mlp1024<<<153,256,0,stream>>>(Wv2,bv2,tcvp+1024,3072,kvoca,512,512,
                                    Wp2,bp2,tcvp+2048,3072,kpos,128);
    k_posz<<<16,256,0,stream>>>(tcvp,Wc2,bc2,WP,bP,kpos,pmask,tw,ta,tz,loss,t);
    k_vocab<<<8000,256,0,stream>>>(emb,kvoca,lg);
    k_vred<<<16,256,0,stream>>>(lg,tw,tz,loss,t);
  }
  k_out<<<1,1,0,stream>>>(loss,(float*)d_out);
}

// Round 2
// 12597.298 us; speedup vs baseline: 2.3107x; 2.3107x over previous
//
#include <hip/hip_runtime.h>
#include <math.h>

#define TT 96
#define VV 32000
#define EPSF 1e-8f

__device__ __forceinline__ float wsum64(float v){
  #pragma unroll
  for (int m=32;m>0;m>>=1) v += __shfl_xor(v,m);
  return v;
}
__device__ __forceinline__ float sigm(float x){ return 1.0f/(1.0f+expf(-x)); }
__device__ __forceinline__ float softplus(float x){ return x>20.0f ? x : log1pf(expf(x)); }
__device__ __forceinline__ float blo(unsigned u){ return __uint_as_float(u<<16); }
__device__ __forceinline__ float bhi(unsigned u){ return __uint_as_float(u & 0xffff0000u); }

// Core: 4 rows/wave, 16 cols (4 col-groups of 4), K-chunk of 512 split over 16 lanes.
// xl stride 129 float4 per col (bank-conflict pad). acc[row][colInGroup].
__device__ __forceinline__ void core_chunk(
  const float4* __restrict__ w0, const float4* __restrict__ w1,
  const float4* __restrict__ w2, const float4* __restrict__ w3,
  const float4* __restrict__ xl, int l, int g, float (&acc)[4][4])
{
  #pragma unroll
  for (int kt=0; kt<8; kt++){
    int i = kt*16 + l;
    float4 a0=w0[i], a1=w1[i], a2=w2[i], a3=w3[i];
    #pragma unroll
    for (int j=0;j<4;j++){
      float4 x = xl[(4*g+j)*129 + i];
      acc[0][j] += a0.x*x.x + a0.y*x.y + a0.z*x.z + a0.w*x.w;
      acc[1][j] += a1.x*x.x + a1.y*x.y + a1.z*x.z + a1.w*x.w;
      acc[2][j] += a2.x*x.x + a2.y*x.y + a2.z*x.z + a2.w*x.w;
      acc[3][j] += a3.x*x.x + a3.y*x.y + a3.z*x.z + a3.w*x.w;
    }
  }
}

// Reduce over the 16 K-split lanes; lane l returns value for (row=l>>2, col=l&3).
__device__ __forceinline__ float reduce_pick(float (&acc)[4][4], int l){
  float r = 0.f;
  #pragma unroll
  for (int ri=0;ri<4;ri++)
  #pragma unroll
  for (int j=0;j<4;j++){
    float v = acc[ri][j];
    v += __shfl_xor(v,1); v += __shfl_xor(v,2);
    v += __shfl_xor(v,4); v += __shfl_xor(v,8);
    if (l == ri*4+j) r = v;
  }
  return r;
}

// ---------------- per-step kernels ----------------

// gates[b][r] = Whh[r]@h[b] + P_w[b,t,r] + (aidx>=0 ? P_a[b,aidx,r] : 0)
__global__ __launch_bounds__(256) void k_gates(
  const float* __restrict__ Whh, const float* __restrict__ h,
  const float* __restrict__ Pw, const float* __restrict__ Pa,
  const int* __restrict__ aidx, float* __restrict__ gates, int t)
{
  __shared__ float4 xl[16*129];
  int tid = threadIdx.x, lane = tid & 63, wave = tid >> 6;
  int l = lane & 15, g = lane >> 4;
  int row0 = blockIdx.x*16 + wave*4;
  const float4* h4 = (const float4*)h;
  float acc[4][4] = {};
  for (int kc=0; kc<2; kc++){
    for (int idx=tid; idx<2048; idx+=256){
      int b = idx>>7, i = idx&127;
      xl[b*129+i] = h4[b*256 + kc*128 + i];
    }
    __syncthreads();
    const float4* w0 = (const float4*)(Whh + (size_t)(row0+0)*1024) + kc*128;
    const float4* w1 = (const float4*)(Whh + (size_t)(row0+1)*1024) + kc*128;
    const float4* w2 = (const float4*)(Whh + (size_t)(row0+2)*1024) + kc*128;
    const float4* w3 = (const float4*)(Whh + (size_t)(row0+3)*1024) + kc*128;
    core_chunk(w0,w1,w2,w3, xl, l, g, acc);
    __syncthreads();
  }
  float v = reduce_pick(acc, l);
  int row = row0 + (l>>2);
  int b = g*4 + (l&3);
  int ai = aidx[b];
  float e = Pw[((size_t)(b*96 + t))*4096 + row];
  if (ai >= 0) e += Pa[((size_t)(b*64 + ai))*4096 + row];
  gates[b*4096 + row] = v + e;
}

__global__ void k_lstm(const float* __restrict__ gates, float* __restrict__ c,
                       float* __restrict__ h)
{
  int b = blockIdx.x, j = blockIdx.y*256 + threadIdx.x;
  const float* gb = gates + b*4096;
  float ig = gb[j], fg = gb[1024+j], gg = gb[2048+j], og = gb[3072+j];
  float co = c[b*1024+j];
  float cn = sigm(fg)*co + sigm(ig)*tanhf(gg);
  c[b*1024+j] = cn;
  h[b*1024+j] = sigm(og)*tanhf(cn);
}

// H1[b][0:1024]   = relu(Wf1_h@h + cf)   (= tf, cf includes bf1 + e_k part)
// H1[b][1024+..]  = Wc1_h@h, Wv1_h@h, Wp1_h@h  (raw; a-part+bias+relu added in k_attn)
__global__ __launch_bounds__(256) void k_heads1(
  const float* __restrict__ Wf1, const float* __restrict__ Wc1,
  const float* __restrict__ Wv1, const float* __restrict__ Wp1,
  const float* __restrict__ h, const float* __restrict__ cf,
  float* __restrict__ H1)
{
  __shared__ float4 xl[16*129];
  int tid = threadIdx.x, lane = tid & 63, wave = tid >> 6;
  int l = lane & 15, g = lane >> 4;
  int seg = blockIdx.x >> 6;
  int rl0 = (blockIdx.x & 63)*16 + wave*4;
  const float* W = (seg==0)?Wf1:(seg==1)?Wc1:(seg==2)?Wv1:Wp1;
  const float4* h4 = (const float4*)h;
  float acc[4][4] = {};
  for (int kc=0; kc<2; kc++){
    for (int idx=tid; idx<2048; idx+=256){
      int b = idx>>7, i = idx&127;
      xl[b*129+i] = h4[b*256 + kc*128 + i];
    }
    __syncthreads();
    const float4* w0 = (const float4*)(W + (size_t)(rl0+0)*1536) + kc*128;
    const float4* w1 = (const float4*)(W + (size_t)(rl0+1)*1536) + kc*128;
    const float4* w2 = (const float4*)(W + (size_t)(rl0+2)*1536) + kc*128;
    const float4* w3 = (const float4*)(W + (size_t)(rl0+3)*1536) + kc*128;
    core_chunk(w0,w1,w2,w3, xl, l, g, acc);
    __syncthreads();
  }
  float v = reduce_pick(acc, l);
  int rl = rl0 + (l>>2);
  int b = g*4 + (l&3);
  if (seg==0) v = fmaxf(v + cf[b*1024 + rl], 0.f);
  H1[b*4096 + seg*1024 + rl] = v;
}

// kfact[b] = Wf2 @ tf(b) + bf2
__global__ __launch_bounds__(256) void k_fk(
  const float* __restrict__ Wf2, const float* __restrict__ bf2,
  const float* __restrict__ H1, float* __restrict__ kfact)
{
  __shared__ float4 xl[16*129];
  int tid = threadIdx.x, lane = tid & 63, wave = tid >> 6;
  int l = lane & 15, g = lane >> 4;
  int row0 = blockIdx.x*16 + wave*4;
  const float4* X4 = (const float4*)H1;   // stride 1024 f4 per b, tf at offset 0
  float acc[4][4] = {};
  for (int kc=0; kc<2; kc++){
    for (int idx=tid; idx<2048; idx+=256){
      int b = idx>>7, i = idx&127;
      xl[b*129+i] = X4[b*1024 + kc*128 + i];
    }
    __syncthreads();
    const float4* w0 = (const float4*)(Wf2 + (size_t)(row0+0)*1024) + kc*128;
    const float4* w1 = (const float4*)(Wf2 + (size_t)(row0+1)*1024) + kc*128;
    const float4* w2 = (const float4*)(Wf2 + (size_t)(row0+2)*1024) + kc*128;
    const float4* w3 = (const float4*)(Wf2 + (size_t)(row0+3)*1024) + kc*128;
    core_chunk(w0,w1,w2,w3, xl, l, g, acc);
    __syncthreads();
  }
  float v = reduce_pick(acc, l);
  int row = row0 + (l>>2);
  int b = g*4 + (l&3);
  kfact[b*512 + row] = v + bf2[row];
}

// attention scores (fp32), masked softmax+eps, loss_m, argmax; then finish c/v/p
// first layers: tcvp = relu(H1_raw + P_h[b,aidx] + bias)
__global__ __launch_bounds__(256) void k_attn(
  const float* __restrict__ fe, const float* __restrict__ kfact,
  const int* __restrict__ ta, const int* __restrict__ nfp,
  const float* __restrict__ H1, const float* __restrict__ Ph,
  const float* __restrict__ bc1, const float* __restrict__ bv1,
  const float* __restrict__ bp1,
  float* __restrict__ tcvp, int* __restrict__ aidx,
  float* __restrict__ loss, int t)
{
  __shared__ float sS[64];
  __shared__ int sIdx;
  int b = blockIdx.x, tid = threadIdx.x;
  int f = tid >> 2, q = tid & 3;
  const float4* fe4 = (const float4*)(fe + ((size_t)b*64 + f)*512);
  const float4* kf4 = (const float4*)(kfact + b*512);
  float acc = 0.f;
  for (int j=0;j<32;j++){
    int i = q*32 + j;
    float4 a = fe4[i], k = kf4[i];
    acc += a.x*k.x + a.y*k.y + a.z*k.z + a.w*k.w;
  }
  acc += __shfl_xor(acc,1);
  acc += __shfl_xor(acc,2);
  if (q==0) sS[f] = acc;
  __syncthreads();
  if (tid < 64){
    int nf = nfp[b];
    float s = sS[tid];
    float mx = s;
    #pragma unroll
    for (int m=32;m>0;m>>=1) mx = fmaxf(mx, __shfl_xor(mx,m));
    float p = expf(s - mx);
    float ps = wsum64(p);
    p /= ps;
    bool mask = (tid < nf) || (tid == 63);
    float mval = mask ? (p + EPSF) : EPSF;
    float msum = wsum64(mval);
    float bv = mval; int bi2 = tid;
    #pragma unroll
    for (int m=32;m>0;m>>=1){
      float ov = __shfl_xor(bv,m); int oi = __shfl_xor(bi2,m);
      if (ov > bv || (ov == bv && oi < bi2)){ bv = ov; bi2 = oi; }
    }
    int at = ta[b*TT + t];
    float mat = __shfl(mval, at);
    if (tid == 0){
      atomicAdd(loss, -(logf(mat) - logf(msum)));
      sIdx = bi2;
    }
  }
  __syncthreads();
  int ai = sIdx;
  if (tid==0) aidx[b] = ai;
  const float* ph = Ph + ((size_t)(b*64 + ai))*3072;
  for (int i2=tid; i2<3072; i2+=256){
    int hd = i2 >> 10, rl = i2 & 1023;
    float bias = (hd==0?bc1:hd==1?bv1:bp1)[rl];
    float v = H1[b*4096 + 1024 + i2] + ph[i2] + bias;
    tcvp[b*3072 + i2] = fmaxf(v, 0.f);
  }
}

// kvoca = Wv2@tv + bv2 ; kpos = Wp2@tp + bp2 ; zlog = Wc2@tc + bc2
__global__ __launch_bounds__(256) void k_heads2(
  const float* __restrict__ Wv2, const float* __restrict__ bv2,
  const float* __restrict__ Wp2, const float* __restrict__ bp2,
  const float* __restrict__ Wc2, const float* __restrict__ bc2,
  const float* __restrict__ tcvp,
  float* __restrict__ kvoca, float* __restrict__ kpos, float* __restrict__ zlog)
{
  __shared__ float4 xl[16*129];
  int tid = threadIdx.x, lane = tid & 63, wave = tid >> 6;
  int l = lane & 15, g = lane >> 4;
  int seg = (blockIdx.x < 32) ? 0 : (blockIdx.x < 39) ? 1 : 2;
  int rb  = (seg==0) ? blockIdx.x*16 : (seg==1) ? (blockIdx.x-32)*16 : 0;
  int rl0 = rb + wave*4;
  const float* WS = (seg==0)?Wv2:(seg==1)?Wp2:Wc2;
  int maxr = (seg==0)?511:(seg==1)?99:0;
  int xoff = (seg==0)?1024:(seg==1)?2048:0;
  const float4* X4 = (const float4*)tcvp;   // b stride 768 f4
  float acc[4][4] = {};
  for (int kc=0; kc<2; kc++){
    for (int idx=tid; idx<2048; idx+=256){
      int b = idx>>7, i = idx&127;
      xl[b*129+i] = X4[b*768 + (xoff>>2) + kc*128 + i];
    }
    __syncthreads();
    const float4* w0 = (const float4*)(WS + (size_t)min(rl0+0,maxr)*1024) + kc*128;
    const float4* w1 = (const float4*)(WS + (size_t)min(rl0+1,maxr)*1024) + kc*128;
    const float4* w2 = (const float4*)(WS + (size_t)min(rl0+2,maxr)*1024) + kc*128;
    const float4* w3 = (const float4*)(WS + (size_t)min(rl0+3,maxr)*1024) + kc*128;
    core_chunk(w0,w1,w2,w3, xl, l, g, acc);
    __syncthreads();
  }
  float v = reduce_pick(acc, l);
  int rl = rl0 + (l>>2);
  int b = g*4 + (l&3);
  if (seg==0) kvoca[b*512 + rl] = v + bv2[rl];
  else if (seg==1){ if (rl < 100) kpos[b*128 + rl] = v + bp2[rl]; }
  else { if (rl == 0) zlog[b] = v + bc2[0]; }
}

// lg[v][b] = emb_bf16[v] . kvoca[b]  (fp32 accumulate)
__global__ __launch_bounds__(256) void k_vocab(
  const unsigned* __restrict__ embbf, const float* __restrict__ kv,
  float* __restrict__ lg)
{
  __shared__ float4 xl[16*129];
  int tid = threadIdx.x, lane = tid & 63, wave = tid >> 6;
  int l = lane & 15, g = lane >> 4;
  const float4* kv4 = (const float4*)kv;
  for (int idx=tid; idx<2048; idx+=256){
    int b = idx>>7, i = idx&127;
    xl[b*129+i] = kv4[b*128 + i];
  }
  __syncthreads();
  int row0 = blockIdx.x*16 + wave*4;
  const uint4* e0 = (const uint4*)(embbf + (size_t)(row0+0)*256);
  const uint4* e1 = (const uint4*)(embbf + (size_t)(row0+1)*256);
  const uint4* e2 = (const uint4*)(embbf + (size_t)(row0+2)*256);
  const uint4* e3 = (const uint4*)(embbf + (size_t)(row0+3)*256);
  float acc[4][4] = {};
  #pragma unroll
  for (int kt=0; kt<4; kt++){
    int i = kt*16 + l;           // uint4 index: 8 bf16 = 8 K-elems
    uint4 u0 = e0[i], u1 = e1[i], u2 = e2[i], u3 = e3[i];
    float f0[8], f1[8], f2[8], f3[8];
    f0[0]=blo(u0.x); f0[1]=bhi(u0.x); f0[2]=blo(u0.y); f0[3]=bhi(u0.y);
    f0[4]=blo(u0.z); f0[5]=bhi(u0.z); f0[6]=blo(u0.w); f0[7]=bhi(u0.w);
    f1[0]=blo(u1.x); f1[1]=bhi(u1.x); f1[2]=blo(u1.y); f1[3]=bhi(u1.y);
    f1[4]=blo(u1.z); f1[5]=bhi(u1.z); f1[6]=blo(u1.w); f1[7]=bhi(u1.w);
    f2[0]=blo(u2.x); f2[1]=bhi(u2.x); f2[2]=blo(u2.y); f2[3]=bhi(u2.y);
    f2[4]=blo(u2.z); f2[5]=bhi(u2.z); f2[6]=blo(u2.w); f2[7]=bhi(u2.w);
    f3[0]=blo(u3.x); f3[1]=bhi(u3.x); f3[2]=blo(u3.y); f3[3]=bhi(u3.y);
    f3[4]=blo(u3.z); f3[5]=bhi(u3.z); f3[6]=blo(u3.w); f3[7]=bhi(u3.w);
    #pragma unroll
    for (int j=0;j<4;j++){
      const float4 x0 = xl[(4*g+j)*129 + 2*i];
      const float4 x1 = xl[(4*g+j)*129 + 2*i + 1];
      acc[0][j] += f0[0]*x0.x+f0[1]*x0.y+f0[2]*x0.z+f0[3]*x0.w
                 + f0[4]*x1.x+f0[5]*x1.y+f0[6]*x1.z+f0[7]*x1.w;
      acc[1][j] += f1[0]*x0.x+f1[1]*x0.y+f1[2]*x0.z+f1[3]*x0.w
                 + f1[4]*x1.x+f1[5]*x1.y+f1[6]*x1.z+f1[7]*x1.w;
      acc[2][j] += f2[0]*x0.x+f2[1]*x0.y+f2[2]*x0.z+f2[3]*x0.w
                 + f2[4]*x1.x+f2[5]*x1.y+f2[6]*x1.z+f2[7]*x1.w;
      acc[3][j] += f3[0]*x0.x+f3[1]*x0.y+f3[2]*x0.z+f3[3]*x0.w
                 + f3[4]*x1.x+f3[5]*x1.y+f3[6]*x1.z+f3[7]*x1.w;
    }
  }
  float v = reduce_pick(acc, l);
  int row = row0 + (l>>2);
  int b = g*4 + (l&3);
  lg[(size_t)row*16 + b] = v;
}

// blocks 0-15: vocab logsumexp + loss (z==0); blocks 16-31: z-loss + pos loss
__global__ __launch_bounds__(256) void k_vredposz(
  const float* __restrict__ lg, const float* __restrict__ kpos,
  const float* __restrict__ zlog, const float* __restrict__ WP,
  const float* __restrict__ bP, const float* __restrict__ pmask,
  const int* __restrict__ tw, const int* __restrict__ ta,
  const int* __restrict__ tz, float* __restrict__ loss, int t)
{
  __shared__ float red[4];
  __shared__ float pp[100];
  int tid = threadIdx.x;
  if (blockIdx.x < 16){
    int b = blockIdx.x;
    float mx = -1e30f;
    for (int v=tid; v<VV; v+=256) mx = fmaxf(mx, lg[(size_t)v*16+b]);
    #pragma unroll
    for (int m=32;m>0;m>>=1) mx = fmaxf(mx, __shfl_xor(mx,m));
    if ((tid&63)==0) red[tid>>6] = mx;
    __syncthreads();
    mx = fmaxf(fmaxf(red[0],red[1]), fmaxf(red[2],red[3]));
    __syncthreads();
    float s = 0.f;
    for (int v=tid; v<VV; v+=256) s += expf(lg[(size_t)v*16+b] - mx);
    s = wsum64(s);
    if ((tid&63)==0) red[tid>>6] = s;
    __syncthreads();
    if (tid==0){
      s = red[0]+red[1]+red[2]+red[3];
      if (tz[b*TT+t]==0){
        int w = tw[b*TT+t];
        float lw = lg[(size_t)w*16+b] - (mx + logf(s));
        atomicAdd(loss, -lw);
      }
    }
  } else {
    int b = blockIdx.x - 16;
    if (tid < 100){
      float s = bP[tid];
      const float* wr = WP + tid*100;
      const float* kp = kpos + b*128;
      for (int j=0;j<100;j++) s += wr[j]*kp[j];
      pp[tid] = s;
    }
    __syncthreads();
    if (tid == 0){
      float u = zlog[b];
      int z = tz[b*TT+t], w = tw[b*TT+t], at = ta[b*TT+t];
      float tot = z ? softplus(-u) : softplus(u);
      if (z){
        float mx = -1e30f;
        for (int l2=0;l2<100;l2++) mx = fmaxf(mx, pp[l2]);
        float se = 0.f;
        for (int l2=0;l2<100;l2++) se += expf(pp[l2]-mx);
        const float* pm = pmask + ((size_t)b*64 + at)*100;
        float msum = 0.f, mw = 0.f;
        for (int l2=0;l2<100;l2++){
          float m = pm[l2]*(expf(pp[l2]-mx)/se) + EPSF;
          msum += m;
          if (l2==w) mw = m;
        }
        tot += -(logf(mw) - logf(msum));
      }
      atomicAdd(loss, tot);
    }
  }
}

// ---------------- once-per-launch kernels ----------------

__global__ void k_cvt_emb(const float* __restrict__ emb, unsigned* __restrict__ out){
  const int n = VV*512/2;
  for (int idx = blockIdx.x*256 + threadIdx.x; idx < n; idx += gridDim.x*256){
    float2 v = ((const float2*)emb)[idx];
    unsigned a = __float_as_uint(v.x), b = __float_as_uint(v.y);
    unsigned ra = (a + 0x7fffu + ((a>>16)&1u)) >> 16;
    unsigned rb = (b + 0x7fffu + ((b>>16)&1u)) >> 16;
    out[idx] = ra | (rb<<16);
  }
}

__global__ void k_setup(const float* __restrict__ fe, const int* __restrict__ nfp,
                        float* __restrict__ e_k, int* __restrict__ aidx){
  int b = blockIdx.x, tid = threadIdx.x;
  int nf = nfp[b];
  for (int d=tid; d<512; d+=256){
    float s = 0.f;
    for (int f=0; f<nf; f++) s += fe[((size_t)b*64+f)*512 + d];
    e_k[b*512+d] = s/(float)nf;
  }
  if (tid==0) aidx[b] = -1;
}

// P_a[c][r] = Wih[r, 0:512] @ fe[c]   (c = b*64+f)
__global__ __launch_bounds__(256) void k_pre_pa(
  const float* __restrict__ Wih, const float* __restrict__ fe, float* __restrict__ Pa)
{
  __shared__ float4 xl[16*129];
  int tid = threadIdx.x, lane = tid & 63, wave = tid >> 6;
  int l = lane & 15, g = lane >> 4;
  int row0 = blockIdx.x*16 + wave*4;
  int c0 = blockIdx.y*16;
  const float4* fe4 = (const float4*)fe;
  for (int idx=tid; idx<2048; idx+=256){
    int cc = idx>>7, i = idx&127;
    xl[cc*129+i] = fe4[(size_t)(c0+cc)*128 + i];
  }
  __syncthreads();
  const float4* w0 = (const float4*)(Wih + (size_t)(row0+0)*1124);
  const float4* w1 = (const float4*)(Wih + (size_t)(row0+1)*1124);
  const float4* w2 = (const float4*)(Wih + (size_t)(row0+2)*1124);
  const float4* w3 = (const float4*)(Wih + (size_t)(row0+3)*1124);
  float acc[4][4] = {};
  core_chunk(w0,w1,w2,w3, xl, l, g, acc);
  float v = reduce_pick(acc, l);
  int row = row0 + (l>>2), c = c0 + g*4 + (l&3);
  Pa[(size_t)c*4096 + row] = v;
}

// P_h[c][r] = W{c,v,p}1[rl, 1024:1536] @ fe[c]
__global__ __launch_bounds__(256) void k_pre_ph(
  const float* __restrict__ Wc1, const float* __restrict__ Wv1,
  const float* __restrict__ Wp1, const float* __restrict__ fe, float* __restrict__ Ph)
{
  __shared__ float4 xl[16*129];
  int tid = threadIdx.x, lane = tid & 63, wave = tid >> 6;
  int l = lane & 15, g = lane >> 4;
  int row0 = blockIdx.x*16 + wave*4;
  int head = row0 >> 10, rl0 = row0 & 1023;
  const float* W = (head==0)?Wc1:(head==1)?Wv1:Wp1;
  int c0 = blockIdx.y*16;
  const float4* fe4 = (const float4*)fe;
  for (int idx=tid; idx<2048; idx+=256){
    int cc = idx>>7, i = idx&127;
    xl[cc*129+i] = fe4[(size_t)(c0+cc)*128 + i];
  }
  __syncthreads();
  const float4* w0 = (const float4*)(W + (size_t)(rl0+0)*1536 + 1024);
  const float4* w1 = (const float4*)(W + (size_t)(rl0+1)*1536 + 1024);
  const float4* w2 = (const float4*)(W + (size_t)(rl0+2)*1536 + 1024);
  const float4* w3 = (const float4*)(W + (size_t)(rl0+3)*1536 + 1024);
  float acc[4][4] = {};
  core_chunk(w0,w1,w2,w3, xl, l, g, acc);
  float v = reduce_pick(acc, l);
  int row = row0 + (l>>2), c = c0 + g*4 + (l&3);
  Ph[(size_t)c*3072 + row] = v;
}

// P_w[c][r] (c=b*96+tt): Wih[r,512:1024]@wv + Wih[r,1024+w]*[z] + b_ih[r]+b_hh[r]
__global__ __launch_bounds__(256) void k_pre_pw(
  const float* __restrict__ Wih, const float* __restrict__ emb,
  const int* __restrict__ tw, const int* __restrict__ tz,
  const float* __restrict__ bih, const float* __restrict__ bhh,
  float* __restrict__ Pw)
{
  __shared__ float4 xl[16*129];
  int tid = threadIdx.x, lane = tid & 63, wave = tid >> 6;
  int l = lane & 15, g = lane >> 4;
  int row0 = blockIdx.x*16 + wave*4;
  int c0 = blockIdx.y*16;
  for (int idx=tid; idx<2048; idx+=256){
    int cc = idx>>7, i = idx&127;
    int c = c0+cc, b = c/96, t2 = c - b*96;
    int w=0, z=0;
    if (t2>0){ w = tw[b*96+t2-1]; z = tz[b*96+t2-1]; }
    float4 v = make_float4(0.f,0.f,0.f,0.f);
    if (z==0) v = ((const float4*)emb)[(size_t)w*128 + i];
    xl[cc*129+i] = v;
  }
  __syncthreads();
  const float4* w0 = (const float4*)(Wih + (size_t)(row0+0)*1124 + 512);
  const float4* w1 = (const float4*)(Wih + (size_t)(row0+1)*1124 + 512);
  const float4* w2 = (const float4*)(Wih + (size_t)(row0+2)*1124 + 512);
  const float4* w3 = (const float4*)(Wih + (size_t)(row0+3)*1124 + 512);
  float acc[4][4] = {};
  core_chunk(w0,w1,w2,w3, xl, l, g, acc);
  float v = reduce_pick(acc, l);
  int row = row0 + (l>>2), c = c0 + g*4 + (l&3);
  int b = c/96, t2 = c - b*96;
  int w=0, z=0;
  if (t2>0){ w = tw[b*96+t2-1]; z = tz[b*96+t2-1]; }
  v += bih[row] + bhh[row];
  if (z) v += Wih[(size_t)row*1124 + 1024 + w];
  Pw[(size_t)c*4096 + row] = v;
}

// cf[b][r] = Wf1[r, 1024:1536] @ e_k[b] + bf1[r]
__global__ __launch_bounds__(256) void k_pre_cf(
  const float* __restrict__ Wf1, const float* __restrict__ bf1,
  const float* __restrict__ e_k, float* __restrict__ cf)
{
  __shared__ float4 xl[16*129];
  int tid = threadIdx.x, lane = tid & 63, wave = tid >> 6;
  int l = lane & 15, g = lane >> 4;
  int row0 = blockIdx.x*16 + wave*4;
  const float4* ek4 = (const float4*)e_k;
  for (int idx=tid; idx<2048; idx+=256){
    int cc = idx>>7, i = idx&127;
    xl[cc*129+i] = ek4[cc*128 + i];
  }
  __syncthreads();
  const float4* w0 = (const float4*)(Wf1 + (size_t)(row0+0)*1536 + 1024);
  const float4* w1 = (const float4*)(Wf1 + (size_t)(row0+1)*1536 + 1024);
  const float4* w2 = (const float4*)(Wf1 + (size_t)(row0+2)*1536 + 1024);
  const float4* w3 = (const float4*)(Wf1 + (size_t)(row0+3)*1536 + 1024);
  float acc[4][4] = {};
  core_chunk(w0,w1,w2,w3, xl, l, g, acc);
  float v = reduce_pick(acc, l);
  int row = row0 + (l>>2), b = g*4 + (l&3);
  cf[b*1024 + row] = v + bf1[row];
}

__global__ void k_out(const float* __restrict__ loss, float* __restrict__ out){
  out[0] = loss[0];
}

extern "C" void kernel_launch(void* const* d_in, const int* in_sizes, int n_in,
                              void* d_out, int out_size, void* d_ws, size_t ws_size,
                              hipStream_t stream)
{
  const float* fe   = (const float*)d_in[0];
  const float* pmask= (const float*)d_in[1];
  const float* emb  = (const float*)d_in[2];
  const float* Wih  = (const float*)d_in[3];
  const float* Whh  = (const float*)d_in[4];
  const float* bih  = (const float*)d_in[5];
  const float* bhh  = (const float*)d_in[6];
  const float* Wf1  = (const float*)d_in[7];
  const float* bf1  = (const float*)d_in[8];
  const float* Wf2  = (const float*)d_in[9];
  const float* bf2  = (const float*)d_in[10];
  const float* Wc1  = (const float*)d_in[11];
  const float* bc1  = (const float*)d_in[12];
  const float* Wc2  = (const float*)d_in[13];
  const float* bc2  = (const float*)d_in[14];
  const float* Wv1  = (const float*)d_in[15];
  const float* bv1  = (const float*)d_in[16];
  const float* Wv2  = (const float*)d_in[17];
  const float* bv2  = (const float*)d_in[18];
  const float* Wp1  = (const float*)d_in[19];
  const float* bp1  = (const float*)d_in[20];
  const float* Wp2  = (const float*)d_in[21];
  const float* bp2  = (const float*)d_in[22];
  const float* WP   = (const float*)d_in[23];
  const float* bP   = (const float*)d_in[24];
  const int* tw  = (const int*)d_in[25];
  const int* ta  = (const int*)d_in[26];
  const int* tz  = (const int*)d_in[27];
  const int* nfp = (const int*)d_in[28];

  float* w = (float*)d_ws;
  float*    loss  = w + 0;         // 16
  float*    h     = w + 16;        // 16384
  float*    c     = w + 16400;     // 16384
  int*      aidx  = (int*)(w + 32784);   // 16
  float*    e_k   = w + 32800;     // 8192
  float*    gates = w + 40992;     // 65536
  float*    H1    = w + 106528;    // 65536
  float*    kfact = w + 172064;    // 8192
  float*    tcvp  = w + 180256;    // 49152
  float*    kvoca = w + 229408;    // 8192
  float*    kpos  = w + 237600;    // 2048
  float*    zlog  = w + 239648;    // 16
  float*    cf    = w + 239664;    // 16384
  float*    lg    = w + 256048;    // 512000
  float*    Pa    = w + 768048;    // 4194304
  float*    Ph    = w + 4962352;   // 3145728
  float*    Pw    = w + 8108080;   // 6291456
  unsigned* embbf = (unsigned*)(w + 14399536); // 8192000 uints

  hipMemsetAsync(d_ws, 0, 131264, stream);   // loss, h, c, aidx region
  k_cvt_emb<<<8192,256,0,stream>>>(emb, embbf);
  k_setup<<<16,256,0,stream>>>(fe, nfp, e_k, aidx);
  k_pre_pa<<<dim3(256,64),256,0,stream>>>(Wih, fe, Pa);
  k_pre_ph<<<dim3(192,64),256,0,stream>>>(Wc1, Wv1, Wp1, fe, Ph);
  k_pre_pw<<<dim3(256,96),256,0,stream>>>(Wih, emb, tw, tz, bih, bhh, Pw);
  k_pre_cf<<<64,256,0,stream>>>(Wf1, bf1, e_k, cf);

  for (int t=0; t<TT; t++){
    k_gates<<<256,256,0,stream>>>(Whh, h, Pw, Pa, aidx, gates, t);
    k_lstm<<<dim3(16,4),256,0,stream>>>(gates, c, h);
    k_heads1<<<256,256,0,stream>>>(Wf1, Wc1, Wv1, Wp1, h, cf, H1);
    k_fk<<<32,256,0,stream>>>(Wf2, bf2, H1, kfact);
    k_attn<<<16,256,0,stream>>>(fe, kfact, ta, nfp, H1, Ph, bc1, bv1, bp1,
                                tcvp, aidx, loss, t);
    k_heads2<<<40,256,0,stream>>>(Wv2, bv2, Wp2, bp2, Wc2, bc2, tcvp,
                                  kvoca, kpos, zlog);
    k_vocab<<<2000,256,0,stream>>>(embbf, kvoca, lg);
    k_vredposz<<<32,256,0,stream>>>(lg, kpos, zlog, WP, bP, pmask,
                                    tw, ta, tz, loss, t);
  }
  k_out<<<1,1,0,stream>>>(loss, (float*)d_out);
}

// Round 3
// 5384.339 us; speedup vs baseline: 5.4061x; 2.3396x over previous
//
#include <hip/hip_runtime.h>
#include <math.h>

#define TT 96
#define VV 32000
#define EPSF 1e-8f

typedef __attribute__((ext_vector_type(8))) short short8;
typedef __attribute__((ext_vector_type(4))) float f4v;

__device__ __forceinline__ float wsum64(float v){
  #pragma unroll
  for (int m=32;m>0;m>>=1) v += __shfl_xor(v,m);
  return v;
}
__device__ __forceinline__ float sigm(float x){ return 1.0f/(1.0f+expf(-x)); }
__device__ __forceinline__ float softplus(float x){ return x>20.0f ? x : log1pf(expf(x)); }
__device__ __forceinline__ float bf2f(unsigned short u){ return __uint_as_float(((unsigned)u)<<16); }
__device__ __forceinline__ unsigned short f2bf(float f){
  unsigned u = __float_as_uint(f);
  return (unsigned short)((u + 0x7fffu + ((u>>16)&1u)) >> 16);
}

// Core: 4 rows/wave, 16 cols (4 col-groups of 4), K-chunk of 512 split over 16 lanes.
__device__ __forceinline__ void core_chunk(
  const float4* __restrict__ w0, const float4* __restrict__ w1,
  const float4* __restrict__ w2, const float4* __restrict__ w3,
  const float4* __restrict__ xl, int l, int g, float (&acc)[4][4])
{
  #pragma unroll
  for (int kt=0; kt<8; kt++){
    int i = kt*16 + l;
    float4 a0=w0[i], a1=w1[i], a2=w2[i], a3=w3[i];
    #pragma unroll
    for (int j=0;j<4;j++){
      float4 x = xl[(4*g+j)*129 + i];
      acc[0][j] += a0.x*x.x + a0.y*x.y + a0.z*x.z + a0.w*x.w;
      acc[1][j] += a1.x*x.x + a1.y*x.y + a1.z*x.z + a1.w*x.w;
      acc[2][j] += a2.x*x.x + a2.y*x.y + a2.z*x.z + a2.w*x.w;
      acc[3][j] += a3.x*x.x + a3.y*x.y + a3.z*x.z + a3.w*x.w;
    }
  }
}

__device__ __forceinline__ float reduce_pick(float (&acc)[4][4], int l){
  float r = 0.f;
  #pragma unroll
  for (int ri=0;ri<4;ri++)
  #pragma unroll
  for (int j=0;j<4;j++){
    float v = acc[ri][j];
    v += __shfl_xor(v,1); v += __shfl_xor(v,2);
    v += __shfl_xor(v,4); v += __shfl_xor(v,8);
    if (l == ri*4+j) r = v;
  }
  return r;
}

// ---------------- phase 1: sequential recurrence ----------------

// gates + LSTM pointwise fused. Block handles 4 js x 4 gates x 16 b.
__global__ __launch_bounds__(256) void k_step1(
  const float* __restrict__ Whh, float* __restrict__ hall,
  const float* __restrict__ Pw, const float* __restrict__ Pa,
  const int* __restrict__ aall, float* __restrict__ c, int t)
{
  __shared__ float4 xl[16*129];
  __shared__ float sg[256];
  int tid = threadIdx.x, lane = tid & 63, wave = tid >> 6;
  int l = lane & 15, g = lane >> 4;
  int j0 = blockIdx.x*4;
  const float4* h4 = (const float4*)hall + (size_t)t*4096;  // slot t
  float acc[4][4] = {};
  for (int kc=0; kc<2; kc++){
    for (int idx=tid; idx<2048; idx+=256){
      int b = idx>>7, i = idx&127;
      xl[b*129+i] = h4[b*256 + kc*128 + i];
    }
    __syncthreads();
    const float4* w0 = (const float4*)(Whh + (size_t)(wave*1024 + j0+0)*1024) + kc*128;
    const float4* w1 = (const float4*)(Whh + (size_t)(wave*1024 + j0+1)*1024) + kc*128;
    const float4* w2 = (const float4*)(Whh + (size_t)(wave*1024 + j0+2)*1024) + kc*128;
    const float4* w3 = (const float4*)(Whh + (size_t)(wave*1024 + j0+3)*1024) + kc*128;
    core_chunk(w0,w1,w2,w3, xl, l, g, acc);
    __syncthreads();
  }
  float v = reduce_pick(acc, l);
  int r = l>>2;
  int b = g*4 + (l&3);
  int row = wave*1024 + j0 + r;
  float e = Pw[((size_t)(b*96+t))*4096 + row];
  if (t > 0){
    int ai = aall[(t-1)*16 + b];
    e += Pa[((size_t)(b*64+ai))*4096 + row];
  }
  sg[wave*64 + r*16 + b] = v + e;
  __syncthreads();
  if (tid < 64){
    int jj = j0 + (tid>>4), bb = tid&15;
    float ig = sg[  0 + (tid>>4)*16 + bb];
    float fg = sg[ 64 + (tid>>4)*16 + bb];
    float gg = sg[128 + (tid>>4)*16 + bb];
    float og = sg[192 + (tid>>4)*16 + bb];
    int ci = bb*1024 + jj;
    float cn = sigm(fg)*c[ci] + sigm(ig)*tanhf(gg);
    c[ci] = cn;
    hall[((size_t)(t+1)*16 + bb)*1024 + jj] = sigm(og)*tanhf(cn);
  }
}

// tf = relu(Wf1_h @ h_t + cf)
__global__ __launch_bounds__(256) void k_tf(
  const float* __restrict__ Wf1, const float* __restrict__ hall,
  const float* __restrict__ cf, float* __restrict__ tf, int t)
{
  __shared__ float4 xl[16*129];
  int tid = threadIdx.x, lane = tid & 63, wave = tid >> 6;
  int l = lane & 15, g = lane >> 4;
  int rl0 = blockIdx.x*16 + wave*4;
  const float4* h4 = (const float4*)hall + (size_t)(t+1)*4096;
  float acc[4][4] = {};
  for (int kc=0; kc<2; kc++){
    for (int idx=tid; idx<2048; idx+=256){
      int b = idx>>7, i = idx&127;
      xl[b*129+i] = h4[b*256 + kc*128 + i];
    }
    __syncthreads();
    const float4* w0 = (const float4*)(Wf1 + (size_t)(rl0+0)*1536) + kc*128;
    const float4* w1 = (const float4*)(Wf1 + (size_t)(rl0+1)*1536) + kc*128;
    const float4* w2 = (const float4*)(Wf1 + (size_t)(rl0+2)*1536) + kc*128;
    const float4* w3 = (const float4*)(Wf1 + (size_t)(rl0+3)*1536) + kc*128;
    core_chunk(w0,w1,w2,w3, xl, l, g, acc);
    __syncthreads();
  }
  float v = reduce_pick(acc, l);
  int rl = rl0 + (l>>2);
  int b = g*4 + (l&3);
  tf[b*1024 + rl] = fmaxf(v + cf[b*1024 + rl], 0.f);
}

// kfact = Wf2 @ tf + bf2
__global__ __launch_bounds__(256) void k_fk(
  const float* __restrict__ Wf2, const float* __restrict__ bf2,
  const float* __restrict__ tf, float* __restrict__ kfact)
{
  __shared__ float4 xl[16*129];
  int tid = threadIdx.x, lane = tid & 63, wave = tid >> 6;
  int l = lane & 15, g = lane >> 4;
  int row0 = blockIdx.x*16 + wave*4;
  const float4* X4 = (const float4*)tf;
  float acc[4][4] = {};
  for (int kc=0; kc<2; kc++){
    for (int idx=tid; idx<2048; idx+=256){
      int b = idx>>7, i = idx&127;
      xl[b*129+i] = X4[b*256 + kc*128 + i];
    }
    __syncthreads();
    const float4* w0 = (const float4*)(Wf2 + (size_t)(row0+0)*1024) + kc*128;
    const float4* w1 = (const float4*)(Wf2 + (size_t)(row0+1)*1024) + kc*128;
    const float4* w2 = (const float4*)(Wf2 + (size_t)(row0+2)*1024) + kc*128;
    const float4* w3 = (const float4*)(Wf2 + (size_t)(row0+3)*1024) + kc*128;
    core_chunk(w0,w1,w2,w3, xl, l, g, acc);
    __syncthreads();
  }
  float v = reduce_pick(acc, l);
  int row = row0 + (l>>2);
  int b = g*4 + (l&3);
  kfact[b*512 + row] = v + bf2[row];
}

// attention: scores, masked softmax+eps, loss_m, argmax -> aall[t*16+b]
__global__ __launch_bounds__(256) void k_attn(
  const float* __restrict__ fe, const float* __restrict__ kfact,
  const int* __restrict__ ta, const int* __restrict__ nfp,
  int* __restrict__ aall, float* __restrict__ loss, int t)
{
  __shared__ float sS[64];
  int b = blockIdx.x, tid = threadIdx.x;
  int f = tid >> 2, q = tid & 3;
  const float4* fe4 = (const float4*)(fe + ((size_t)b*64 + f)*512);
  const float4* kf4 = (const float4*)(kfact + b*512);
  float acc = 0.f;
  for (int j=0;j<32;j++){
    int i = q*32 + j;
    float4 a = fe4[i], k = kf4[i];
    acc += a.x*k.x + a.y*k.y + a.z*k.z + a.w*k.w;
  }
  acc += __shfl_xor(acc,1);
  acc += __shfl_xor(acc,2);
  if (q==0) sS[f] = acc;
  __syncthreads();
  if (tid < 64){
    int nf = nfp[b];
    float s = sS[tid];
    float mx = s;
    #pragma unroll
    for (int m=32;m>0;m>>=1) mx = fmaxf(mx, __shfl_xor(mx,m));
    float p = expf(s - mx);
    float ps = wsum64(p);
    p /= ps;
    bool mask = (tid < nf) || (tid == 63);
    float mval = mask ? (p + EPSF) : EPSF;
    float msum = wsum64(mval);
    float bv = mval; int bi2 = tid;
    #pragma unroll
    for (int m=32;m>0;m>>=1){
      float ov = __shfl_xor(bv,m); int oi = __shfl_xor(bi2,m);
      if (ov > bv || (ov == bv && oi < bi2)){ bv = ov; bi2 = oi; }
    }
    int at = ta[b*TT + t];
    float mat = __shfl(mval, at);
    if (tid == 0){
      atomicAdd(loss, -(logf(mat) - logf(msum)));
      aall[t*16 + b] = bi2;
    }
  }
}

// ---------------- phase 2: batched over all (b,t) ----------------

// tcvp[n] = relu(W{c,v,p}1_h @ h_t + Ph[b,aidx] + bias), n = t*16+b
__global__ __launch_bounds__(256) void k2_cvp(
  const float* __restrict__ Wc1, const float* __restrict__ Wv1,
  const float* __restrict__ Wp1, const float* __restrict__ hall,
  const float* __restrict__ Ph, const int* __restrict__ aall,
  const float* __restrict__ bc1, const float* __restrict__ bv1,
  const float* __restrict__ bp1, float* __restrict__ tcvp)
{
  __shared__ float4 xl[16*129];
  int tid = threadIdx.x, lane = tid & 63, wave = tid >> 6;
  int l = lane & 15, g = lane >> 4;
  int seg = blockIdx.x >> 6;
  int rl0 = (blockIdx.x & 63)*16 + wave*4;
  const float* W = (seg==0)?Wc1:(seg==1)?Wv1:Wp1;
  const float4* h4 = (const float4*)hall + (size_t)(16 + blockIdx.y*16)*256;
  float acc[4][4] = {};
  for (int kc=0; kc<2; kc++){
    for (int idx=tid; idx<2048; idx+=256){
      int cc = idx>>7, i = idx&127;
      xl[cc*129+i] = h4[cc*256 + kc*128 + i];
    }
    __syncthreads();
    const float4* w0 = (const float4*)(W + (size_t)(rl0+0)*1536) + kc*128;
    const float4* w1 = (const float4*)(W + (size_t)(rl0+1)*1536) + kc*128;
    const float4* w2 = (const float4*)(W + (size_t)(rl0+2)*1536) + kc*128;
    const float4* w3 = (const float4*)(W + (size_t)(rl0+3)*1536) + kc*128;
    core_chunk(w0,w1,w2,w3, xl, l, g, acc);
    __syncthreads();
  }
  float v = reduce_pick(acc, l);
  int rl = rl0 + (l>>2);
  int n = blockIdx.y*16 + g*4 + (l&3);
  int b = n & 15;
  int ai = aall[n];
  const float* bias = (seg==0)?bc1:(seg==1)?bv1:bp1;
  float vv = v + Ph[((size_t)(b*64+ai))*3072 + seg*1024 + rl] + bias[rl];
  tcvp[(size_t)n*3072 + seg*1024 + rl] = fmaxf(vv, 0.f);
}

// kvoca(bf16) / kpos / zlog for all n
__global__ __launch_bounds__(256) void k2_heads2(
  const float* __restrict__ Wv2, const float* __restrict__ bv2,
  const float* __restrict__ Wp2, const float* __restrict__ bp2,
  const float* __restrict__ Wc2, const float* __restrict__ bc2,
  const float* __restrict__ tcvp, unsigned short* __restrict__ kvh,
  float* __restrict__ kpall, float* __restrict__ zlall)
{
  __shared__ float4 xl[16*129];
  int tid = threadIdx.x, lane = tid & 63, wave = tid >> 6;
  int l = lane & 15, g = lane >> 4;
  int bx = blockIdx.x;
  int seg = (bx < 32) ? 0 : (bx < 39) ? 1 : 2;
  int rb  = (seg==0) ? bx*16 : (seg==1) ? (bx-32)*16 : 0;
  int rl0 = rb + wave*4;
  const float* WS = (seg==0)?Wv2:(seg==1)?Wp2:Wc2;
  int maxr = (seg==0)?511:(seg==1)?99:0;
  int xoff4 = (seg==0)?256:(seg==1)?512:0;
  const float4* X4 = (const float4*)tcvp;
  float acc[4][4] = {};
  for (int kc=0; kc<2; kc++){
    for (int idx=tid; idx<2048; idx+=256){
      int cc = idx>>7, i = idx&127;
      xl[cc*129+i] = X4[(size_t)(blockIdx.y*16+cc)*768 + xoff4 + kc*128 + i];
    }
    __syncthreads();
    const float4* w0 = (const float4*)(WS + (size_t)min(rl0+0,maxr)*1024) + kc*128;
    const float4* w1 = (const float4*)(WS + (size_t)min(rl0+1,maxr)*1024) + kc*128;
    const float4* w2 = (const float4*)(WS + (size_t)min(rl0+2,maxr)*1024) + kc*128;
    const float4* w3 = (const float4*)(WS + (size_t)min(rl0+3,maxr)*1024) + kc*128;
    core_chunk(w0,w1,w2,w3, xl, l, g, acc);
    __syncthreads();
  }
  float v = reduce_pick(acc, l);
  int rl = rl0 + (l>>2);
  int n = blockIdx.y*16 + g*4 + (l&3);
  if (seg==0) kvh[(size_t)n*512 + rl] = f2bf(v + bv2[rl]);
  else if (seg==1){ if (rl < 100) kpall[n*128 + rl] = v + bp2[rl]; }
  else { if (rl == 0) zlall[n] = v + bc2[0]; }
}

// vocab GEMM (bf16 MFMA, 64x64 per wave) with fused per-64-row logsumexp partials
__global__ __launch_bounds__(256) void k2_vocab(
  const unsigned short* __restrict__ embh, const unsigned short* __restrict__ kvh,
  float2* __restrict__ part)
{
  int wid = blockIdx.x*4 + (threadIdx.x>>6);
  int lane = threadIdx.x & 63;
  int mtile = wid % 500, ntile = wid / 500;
  int mrow = mtile*64 + (lane&15);
  int ncol = ntile*64 + (lane&15);
  int ko = (lane>>4)*8;
  f4v acc[4][4];
  #pragma unroll
  for (int i=0;i<4;i++)
  #pragma unroll
  for (int j=0;j<4;j++)
  #pragma unroll
  for (int r=0;r<4;r++) acc[i][j][r] = 0.f;
  for (int kk=0; kk<512; kk+=32){
    short8 af[4], bfr[4];
    #pragma unroll
    for (int i=0;i<4;i++)
      af[i] = *(const short8*)(embh + (size_t)(mrow+16*i)*512 + kk + ko);
    #pragma unroll
    for (int i=0;i<4;i++)
      bfr[i] = *(const short8*)(kvh + (size_t)(ncol+16*i)*512 + kk + ko);
    #pragma unroll
    for (int i=0;i<4;i++)
      #pragma unroll
      for (int j=0;j<4;j++)
        acc[i][j] = __builtin_amdgcn_mfma_f32_16x16x32_bf16(af[i], bfr[j], acc[i][j], 0,0,0);
  }
  int q = lane>>4;
  #pragma unroll
  for (int j=0;j<4;j++){
    float mx = -3.4e38f;
    #pragma unroll
    for (int i=0;i<4;i++)
    #pragma unroll
    for (int r=0;r<4;r++) mx = fmaxf(mx, acc[i][j][r]);
    mx = fmaxf(mx, __shfl_xor(mx,16));
    mx = fmaxf(mx, __shfl_xor(mx,32));
    float s = 0.f;
    #pragma unroll
    for (int i=0;i<4;i++)
    #pragma unroll
    for (int r=0;r<4;r++) s += expf(acc[i][j][r] - mx);
    s += __shfl_xor(s,16);
    s += __shfl_xor(s,32);
    if (q==0){
      int col = ntile*64 + 16*j + (lane&15);
      part[(size_t)col*500 + mtile] = make_float2(mx, s);
    }
  }
}

// per-n: merge partials -> logZ; direct dot for logit[w]; vocab loss (z==0)
__global__ __launch_bounds__(256) void k2_vfin(
  const float2* __restrict__ part, const unsigned short* __restrict__ embh,
  const unsigned short* __restrict__ kvh, const int* __restrict__ tw,
  const int* __restrict__ tz, float* __restrict__ loss)
{
  __shared__ float red[4];
  int n = blockIdx.x, tid = threadIdx.x;
  int t = n>>4, b = n&15;
  float mx = -3.4e38f;
  for (int i=tid; i<500; i+=256) mx = fmaxf(mx, part[(size_t)n*500+i].x);
  #pragma unroll
  for (int m=32;m>0;m>>=1) mx = fmaxf(mx, __shfl_xor(mx,m));
  if ((tid&63)==0) red[tid>>6] = mx;
  __syncthreads();
  float M = fmaxf(fmaxf(red[0],red[1]), fmaxf(red[2],red[3]));
  __syncthreads();
  float s = 0.f;
  for (int i=tid; i<500; i+=256){
    float2 p = part[(size_t)n*500+i];
    s += p.y * expf(p.x - M);
  }
  s = wsum64(s);
  if ((tid&63)==0) red[tid>>6] = s;
  __syncthreads();
  float S = red[0]+red[1]+red[2]+red[3];
  __syncthreads();
  int w = tw[b*96+t];
  float d = 0.f;
  {
    const unsigned short* er = embh + (size_t)w*512;
    const unsigned short* kr = kvh + (size_t)n*512;
    for (int i=tid; i<512; i+=256) d += bf2f(er[i])*bf2f(kr[i]);
  }
  d = wsum64(d);
  if ((tid&63)==0) red[tid>>6] = d;
  __syncthreads();
  if (tid==0 && tz[b*96+t]==0){
    float D = red[0]+red[1]+red[2]+red[3];
    atomicAdd(loss, -(D - (M + logf(S))));
  }
}

// per-n: z loss + position loss
__global__ __launch_bounds__(128) void k2_posz(
  const float* __restrict__ kpall, const float* __restrict__ zlall,
  const float* __restrict__ WP, const float* __restrict__ bP,
  const float* __restrict__ pmask, const int* __restrict__ tw,
  const int* __restrict__ ta, const int* __restrict__ tz,
  float* __restrict__ loss)
{
  __shared__ float pp[100];
  int n = blockIdx.x, tid = threadIdx.x;
  int t = n>>4, b = n&15;
  if (tid < 100){
    float s = bP[tid];
    const float* wr = WP + tid*100;
    const float* kp = kpall + n*128;
    for (int j=0;j<100;j++) s += wr[j]*kp[j];
    pp[tid] = s;
  }
  __syncthreads();
  if (tid == 0){
    float u = zlall[n];
    int z = tz[b*96+t], w = tw[b*96+t], at = ta[b*96+t];
    float tot = z ? softplus(-u) : softplus(u);
    if (z){
      float mxv = -1e30f;
      for (int l2=0;l2<100;l2++) mxv = fmaxf(mxv, pp[l2]);
      float se = 0.f;
      for (int l2=0;l2<100;l2++) se += expf(pp[l2]-mxv);
      const float* pm = pmask + ((size_t)b*64 + at)*100;
      float msum = 0.f, mw = 0.f;
      for (int l2=0;l2<100;l2++){
        float m = pm[l2]*(expf(pp[l2]-mxv)/se) + EPSF;
        msum += m;
        if (l2==w) mw = m;
      }
      tot += -(logf(mw) - logf(msum));
    }
    atomicAdd(loss, tot);
  }
}

// ---------------- phase 0: once-per-launch precompute ----------------

__global__ void k_cvt_emb(const float* __restrict__ emb, unsigned* __restrict__ out){
  const int n = VV*512/2;
  for (int idx = blockIdx.x*256 + threadIdx.x; idx < n; idx += gridDim.x*256){
    float2 v = ((const float2*)emb)[idx];
    unsigned a = __float_as_uint(v.x), b = __float_as_uint(v.y);
    unsigned ra = (a + 0x7fffu + ((a>>16)&1u)) >> 16;
    unsigned rb = (b + 0x7fffu + ((b>>16)&1u)) >> 16;
    out[idx] = ra | (rb<<16);
  }
}

__global__ void k_setup(const float* __restrict__ fe, const int* __restrict__ nfp,
                        float* __restrict__ e_k){
  int b = blockIdx.x, tid = threadIdx.x;
  int nf = nfp[b];
  for (int d=tid; d<512; d+=256){
    float s = 0.f;
    for (int f=0; f<nf; f++) s += fe[((size_t)b*64+f)*512 + d];
    e_k[b*512+d] = s/(float)nf;
  }
}

__global__ __launch_bounds__(256) void k_pre_pa(
  const float* __restrict__ Wih, const float* __restrict__ fe, float* __restrict__ Pa)
{
  __shared__ float4 xl[16*129];
  int tid = threadIdx.x, lane = tid & 63, wave = tid >> 6;
  int l = lane & 15, g = lane >> 4;
  int row0 = blockIdx.x*16 + wave*4;
  int c0 = blockIdx.y*16;
  const float4* fe4 = (const float4*)fe;
  for (int idx=tid; idx<2048; idx+=256){
    int cc = idx>>7, i = idx&127;
    xl[cc*129+i] = fe4[(size_t)(c0+cc)*128 + i];
  }
  __syncthreads();
  const float4* w0 = (const float4*)(Wih + (size_t)(row0+0)*1124);
  const float4* w1 = (const float4*)(Wih + (size_t)(row0+1)*1124);
  const float4* w2 = (const float4*)(Wih + (size_t)(row0+2)*1124);
  const float4* w3 = (const float4*)(Wih + (size_t)(row0+3)*1124);
  float acc[4][4] = {};
  core_chunk(w0,w1,w2,w3, xl, l, g, acc);
  float v = reduce_pick(acc, l);
  int row = row0 + (l>>2), c = c0 + g*4 + (l&3);
  Pa[(size_t)c*4096 + row] = v;
}

__global__ __launch_bounds__(256) void k_pre_ph(
  const float* __restrict__ Wc1, const float* __restrict__ Wv1,
  const float* __restrict__ Wp1, const float* __restrict__ fe, float* __restrict__ Ph)
{
  __shared__ float4 xl[16*129];
  int tid = threadIdx.x, lane = tid & 63, wave = tid >> 6;
  int l = lane & 15, g = lane >> 4;
  int row0 = blockIdx.x*16 + wave*4;
  int head = row0 >> 10, rl0 = row0 & 1023;
  const float* W = (head==0)?Wc1:(head==1)?Wv1:Wp1;
  int c0 = blockIdx.y*16;
  const float4* fe4 = (const float4*)fe;
  for (int idx=tid; idx<2048; idx+=256){
    int cc = idx>>7, i = idx&127;
    xl[cc*129+i] = fe4[(size_t)(c0+cc)*128 + i];
  }
  __syncthreads();
  const float4* w0 = (const float4*)(W + (size_t)(rl0+0)*1536 + 1024);
  const float4* w1 = (const float4*)(W + (size_t)(rl0+1)*1536 + 1024);
  const float4* w2 = (const float4*)(W + (size_t)(rl0+2)*1536 + 1024);
  const float4* w3 = (const float4*)(W + (size_t)(rl0+3)*1536 + 1024);
  float acc[4][4] = {};
  core_chunk(w0,w1,w2,w3, xl, l, g, acc);
  float v = reduce_pick(acc, l);
  int row = row0 + (l>>2), c = c0 + g*4 + (l&3);
  Ph[(size_t)c*3072 + row] = v;
}

__global__ __launch_bounds__(256) void k_pre_pw(
  const float* __restrict__ Wih, const float* __restrict__ emb,
  const int* __restrict__ tw, const int* __restrict__ tz,
  const float* __restrict__ bih, const float* __restrict__ bhh,
  float* __restrict__ Pw)
{
  __shared__ float4 xl[16*129];
  int tid = threadIdx.x, lane = tid & 63, wave = tid >> 6;
  int l = lane & 15, g = lane >> 4;
  int row0 = blockIdx.x*16 + wave*4;
  int c0 = blockIdx.y*16;
  for (int idx=tid; idx<2048; idx+=256){
    int cc = idx>>7, i = idx&127;
    int c = c0+cc, b = c/96, t2 = c - b*96;
    int w=0, z=0;
    if (t2>0){ w = tw[b*96+t2-1]; z = tz[b*96+t2-1]; }
    float4 v = make_float4(0.f,0.f,0.f,0.f);
    if (z==0) v = ((const float4*)emb)[(size_t)w*128 + i];
    xl[cc*129+i] = v;
  }
  __syncthreads();
  const float4* w0 = (const float4*)(Wih + (size_t)(row0+0)*1124 + 512);
  const float4* w1 = (const float4*)(Wih + (size_t)(row0+1)*1124 + 512);
  const float4* w2 = (const float4*)(Wih + (size_t)(row0+2)*1124 + 512);
  const float4* w3 = (const float4*)(Wih + (size_t)(row0+3)*1124 + 512);
  float acc[4][4] = {};
  core_chunk(w0,w1,w2,w3, xl, l, g, acc);
  float v = reduce_pick(acc, l);
  int row = row0 + (l>>2), c = c0 + g*4 + (l&3);
  int b = c/96, t2 = c - b*96;
  int w=0, z=0;
  if (t2>0){ w = tw[b*96+t2-1]; z = tz[b*96+t2-1]; }
  v += bih[row] + bhh[row];
  if (z) v += Wih[(size_t)row*1124 + 1024 + w];
  Pw[(size_t)c*4096 + row] = v;
}

__global__ __launch_bounds__(256) void k_pre_cf(
  const float* __restrict__ Wf1, const float* __restrict__ bf1,
  const float* __restrict__ e_k, float* __restrict__ cf)
{
  __shared__ float4 xl[16*129];
  int tid = threadIdx.x, lane = tid & 63, wave = tid >> 6;
  int l = lane & 15, g = lane >> 4;
  int row0 = blockIdx.x*16 + wave*4;
  const float4* ek4 = (const float4*)e_k;
  for (int idx=tid; idx<2048; idx+=256){
    int cc = idx>>7, i = idx&127;
    xl[cc*129+i] = ek4[cc*128 + i];
  }
  __syncthreads();
  const float4* w0 = (const float4*)(Wf1 + (size_t)(row0+0)*1536 + 1024);
  const float4* w1 = (const float4*)(Wf1 + (size_t)(row0+1)*1536 + 1024);
  const float4* w2 = (const float4*)(Wf1 + (size_t)(row0+2)*1536 + 1024);
  const float4* w3 = (const float4*)(Wf1 + (size_t)(row0+3)*1536 + 1024);
  float acc[4][4] = {};
  core_chunk(w0,w1,w2,w3, xl, l, g, acc);
  float v = reduce_pick(acc, l);
  int row = row0 + (l>>2), b = g*4 + (l&3);
  cf[b*1024 + row] = v + bf1[row];
}

__global__ void k_out(const float* __restrict__ loss, float* __restrict__ out){
  out[0] = loss[0];
}

extern "C" void kernel_launch(void* const* d_in, const int* in_sizes, int n_in,
                              void* d_out, int out_size, void* d_ws, size_t ws_size,
                              hipStream_t stream)
{
  const float* fe   = (const float*)d_in[0];
  const float* pmask= (const float*)d_in[1];
  const float* emb  = (const float*)d_in[2];
  const float* Wih  = (const float*)d_in[3];
  const float* Whh  = (const float*)d_in[4];
  const float* bih  = (const float*)d_in[5];
  const float* bhh  = (const float*)d_in[6];
  const float* Wf1  = (const float*)d_in[7];
  const float* bf1  = (const float*)d_in[8];
  const float* Wf2  = (const float*)d_in[9];
  const float* bf2  = (const float*)d_in[10];
  const float* Wc1  = (const float*)d_in[11];
  const float* bc1  = (const float*)d_in[12];
  const float* Wc2  = (const float*)d_in[13];
  const float* bc2  = (const float*)d_in[14];
  const float* Wv1  = (const float*)d_in[15];
  const float* bv1  = (const float*)d_in[16];
  const float* Wv2  = (const float*)d_in[17];
  const float* bv2  = (const float*)d_in[18];
  const float* Wp1  = (const float*)d_in[19];
  const float* bp1  = (const float*)d_in[20];
  const float* Wp2  = (const float*)d_in[21];
  const float* bp2  = (const float*)d_in[22];
  const float* WP   = (const float*)d_in[23];
  const float* bP   = (const float*)d_in[24];
  const int* tw  = (const int*)d_in[25];
  const int* ta  = (const int*)d_in[26];
  const int* tz  = (const int*)d_in[27];
  const int* nfp = (const int*)d_in[28];

  float* w = (float*)d_ws;
  float*    loss  = w + 0;                        // 16
  float*    c     = w + 16;                       // 16384
  float*    hall  = w + 16400;                    // 97*16384 = 1589248 (slot0 zeroed)
  int*      aall  = (int*)(w + 1605648);          // 1536
  float*    tf    = w + 1607184;                  // 16384
  float*    kfact = w + 1623568;                  // 8192
  float*    e_k   = w + 1631760;                  // 8192
  float*    cf    = w + 1639952;                  // 16384
  float*    kpall = w + 1656336;                  // 196608
  float*    zlall = w + 1852944;                  // 1536
  float*    tcvp  = w + 1854480;                  // 4718592
  float2*   part  = (float2*)(w + 6573072);       // 1536*500*2 floats
  unsigned short* kvh = (unsigned short*)(w + 8109072);  // 786432 ushorts
  float*    Pa    = w + 8502288;                  // 4194304
  float*    Ph    = w + 12696592;                 // 3145728
  float*    Pw    = w + 15842320;                 // 6291456
  unsigned* embbf = (unsigned*)(w + 22133776);    // 8192000 uints
  const unsigned short* embh = (const unsigned short*)embbf;

  // zero loss, c, hall slot 0
  hipMemsetAsync(d_ws, 0, (size_t)(16 + 16384 + 16384)*4, stream);
  k_cvt_emb<<<8192,256,0,stream>>>(emb, embbf);
  k_setup<<<16,256,0,stream>>>(fe, nfp, e_k);
  k_pre_pa<<<dim3(256,64),256,0,stream>>>(Wih, fe, Pa);
  k_pre_ph<<<dim3(192,64),256,0,stream>>>(Wc1, Wv1, Wp1, fe, Ph);
  k_pre_pw<<<dim3(256,96),256,0,stream>>>(Wih, emb, tw, tz, bih, bhh, Pw);
  k_pre_cf<<<64,256,0,stream>>>(Wf1, bf1, e_k, cf);

  for (int t=0; t<TT; t++){
    k_step1<<<256,256,0,stream>>>(Whh, hall, Pw, Pa, aall, c, t);
    k_tf<<<64,256,0,stream>>>(Wf1, hall, cf, tf, t);
    k_fk<<<32,256,0,stream>>>(Wf2, bf2, tf, kfact);
    k_attn<<<16,256,0,stream>>>(fe, kfact, ta, nfp, aall, loss, t);
  }

  k2_cvp<<<dim3(192,96),256,0,stream>>>(Wc1, Wv1, Wp1, hall, Ph, aall,
                                        bc1, bv1, bp1, tcvp);
  k2_heads2<<<dim3(40,96),256,0,stream>>>(Wv2, bv2, Wp2, bp2, Wc2, bc2,
                                          tcvp, kvh, kpall, zlall);
  k2_vocab<<<3000,256,0,stream>>>(embh, kvh, part);
  k2_vfin<<<1536,256,0,stream>>>(part, embh, kvh, tw, tz, loss);
  k2_posz<<<1536,128,0,stream>>>(kpall, zlall, WP, bP, pmask, tw, ta, tz, loss);
  k_out<<<1,1,0,stream>>>(loss, (float*)d_out);
}